// Round 1
// baseline (165.815 us; speedup 1.0000x reference)
//
#include <hip/hip_runtime.h>

// Chamfer loss: global (data vs rec) + per-part (data seg vs recp seg).
// All roles share the same inner structure: for each A point, min over B
// points of (||b||^2 - 2 a.b), then + ||a||^2; accumulate sum.
// B points staged in LDS as float4(-2bx, -2by, -2bz, ||b||^2) -> pair cost
// = 3 fma + 1 min.

#define N2K 2048
#define N8K 8192
#define TB 2048      // B-tile size staged in LDS (32 KB as float4)
#define THREADS 256
#define NBLK 416     // [0,32)=d2  [32,160)=d1  [160,288)=p1  [288,416)=p2

__global__ __launch_bounds__(THREADS) void chamfer_kernel(
    const float* __restrict__ data,
    const float* __restrict__ rec,
    const float* __restrict__ recp,
    float* __restrict__ partials)
{
    __shared__ float4 sB[TB];
    __shared__ float sred[4];

    const int bid = blockIdx.x;
    const float* Ab; int As; int aOff;
    const float* Bb; int Bs; int bOff; int bCount;

    if (bid < 32) {              // d2: A = rec[b], B = data[b] (4 tiles)
        int t = bid, b = t >> 2, chunk = t & 3;
        Ab = rec  + b * 3 * N2K; As = N2K; aOff = chunk * (THREADS * 2);
        Bb = data + b * 3 * N8K; Bs = N8K; bOff = 0; bCount = N8K;
    } else if (bid < 160) {      // d1: A = data[b], B = rec[b]
        int t = bid - 32, b = t >> 4, chunk = t & 15;
        Ab = data + b * 3 * N8K; As = N8K; aOff = chunk * (THREADS * 2);
        Bb = rec  + b * 3 * N2K; Bs = N2K; bOff = 0; bCount = N2K;
    } else if (bid < 288) {      // p1: A = data seg(b,p), B = recp seg(b,p)
        int t = bid - 160, b = t >> 4, r = t & 15, p = r >> 2, chunk = r & 3;
        Ab = data + b * 3 * N8K; As = N8K; aOff = p * N2K + chunk * (THREADS * 2);
        Bb = recp + b * 3 * N8K; Bs = N8K; bOff = p * N2K; bCount = N2K;
    } else {                     // p2: A = recp seg(b,p), B = data seg(b,p)
        int t = bid - 288, b = t >> 4, r = t & 15, p = r >> 2, chunk = r & 3;
        Ab = recp + b * 3 * N8K; As = N8K; aOff = p * N2K + chunk * (THREADS * 2);
        Bb = data + b * 3 * N8K; Bs = N8K; bOff = p * N2K; bCount = N2K;
    }

    const int tid = threadIdx.x;

    // Two A points per thread (coalesced: tid and tid+256)
    const int i0 = aOff + tid;
    const int i1 = aOff + THREADS + tid;
    const float a0x = Ab[i0], a0y = Ab[As + i0], a0z = Ab[2 * As + i0];
    const float a1x = Ab[i1], a1y = Ab[As + i1], a1z = Ab[2 * As + i1];
    const float na0 = a0x * a0x + a0y * a0y + a0z * a0z;
    const float na1 = a1x * a1x + a1y * a1y + a1z * a1z;

    float m0 = 3.4e38f, m1 = 3.4e38f;

    for (int tile = 0; tile < bCount; tile += TB) {
        if (tile) __syncthreads();            // previous tile's compute done
        for (int k = tid; k < TB; k += THREADS) {
            int j = bOff + tile + k;
            float x = Bb[j], y = Bb[Bs + j], z = Bb[2 * Bs + j];
            sB[k] = make_float4(-2.f * x, -2.f * y, -2.f * z,
                                x * x + y * y + z * z);
        }
        __syncthreads();
        #pragma unroll 8
        for (int j = 0; j < TB; ++j) {        // wave-uniform j -> LDS broadcast
            float4 q = sB[j];
            m0 = fminf(m0, fmaf(a0x, q.x, fmaf(a0y, q.y, fmaf(a0z, q.z, q.w))));
            m1 = fminf(m1, fmaf(a1x, q.x, fmaf(a1y, q.y, fmaf(a1z, q.z, q.w))));
        }
    }

    float v = (na0 + m0) + (na1 + m1);
    #pragma unroll
    for (int o = 32; o > 0; o >>= 1) v += __shfl_down(v, o, 64);
    const int lane = tid & 63, wid = tid >> 6;
    if (lane == 0) sred[wid] = v;
    __syncthreads();
    if (tid == 0) {
        partials[bid] = (sred[0] + sred[1]) + (sred[2] + sred[3]);
    }
}

__global__ __launch_bounds__(512) void finalize_kernel(
    const float* __restrict__ partials, float* __restrict__ out)
{
    __shared__ float sred[8];
    const int tid = threadIdx.x;
    float v = 0.f;
    if (tid < NBLK) {
        // d2 blocks: mean over 8*2048; d1: mean over 8*8192; parts: 8*2048
        float w = (tid >= 32 && tid < 160) ? (1.0f / 65536.f) : (1.0f / 16384.f);
        v = partials[tid] * w;
    }
    #pragma unroll
    for (int o = 32; o > 0; o >>= 1) v += __shfl_down(v, o, 64);
    const int lane = tid & 63, wid = tid >> 6;
    if (lane == 0) sred[wid] = v;
    __syncthreads();
    if (tid == 0) {
        float s = 0.f;
        #pragma unroll
        for (int i = 0; i < 8; ++i) s += sred[i];
        out[0] = s * 0.2f;   // /5
    }
}

extern "C" void kernel_launch(void* const* d_in, const int* in_sizes, int n_in,
                              void* d_out, int out_size, void* d_ws, size_t ws_size,
                              hipStream_t stream) {
    const float* data = (const float*)d_in[0];
    const float* rec  = (const float*)d_in[1];
    const float* recp = (const float*)d_in[2];
    float* out      = (float*)d_out;
    float* partials = (float*)d_ws;

    chamfer_kernel<<<NBLK, THREADS, 0, stream>>>(data, rec, recp, partials);
    finalize_kernel<<<1, 512, 0, stream>>>(partials, out);
}

// Round 2
// 75.260 us; speedup vs baseline: 2.2032x; 2.2032x over previous
//
#include <hip/hip_runtime.h>

// Chamfer loss: global (data vs rec) + per-part (data seg vs recp seg).
// Uniform-work decomposition: 1024 blocks x 256 threads, each block =
// 256 A-points x 2048 B-points. B staged once in LDS as
// float4(-2bx,-2by,-2bz,||b||^2) -> pair cost = 3 fma + 1 min.
// d2 (rec vs data, B=8192) is split into 4 B-chunks; per-A chunk mins go
// to ws and are min-combined in finalize (fixed order, deterministic).

#define N2K 2048
#define N8K 8192
#define THREADS 256
#define NBLK 1024          // 256 per role: [0,256)=d1 [256,512)=d2 [512,768)=p1 [768,1024)=p2
#define D2MINS 16384       // 8 batches * 2048 rec points
#define PARTIALS_OFF 65536 // 4 chunks * 16384 floats of d2 mins first

__global__ __launch_bounds__(THREADS) void chamfer_kernel(
    const float* __restrict__ data,
    const float* __restrict__ rec,
    const float* __restrict__ recp,
    float* __restrict__ ws)
{
    __shared__ float4 sB[N2K];
    __shared__ float sred[4];

    const int bid = blockIdx.x;
    const int role = bid >> 8;     // 0=d1 1=d2 2=p1 3=p2
    const int t = bid & 255;
    const int b = t >> 5;          // batch
    const int r = t & 31;

    const float* Ab; int As; int aOff;
    const float* Bb; int Bs; int bOff;
    int chunk = 0;

    if (role == 0) {               // d1: A=data[b] (32 tiles), B=rec[b]
        Ab = data + b * 3 * N8K; As = N8K; aOff = r * 256;
        Bb = rec  + b * 3 * N2K; Bs = N2K; bOff = 0;
    } else if (role == 1) {        // d2: A=rec[b] (8 tiles), B=data[b] chunk (4)
        chunk = r >> 3; int aTile = r & 7;
        Ab = rec  + b * 3 * N2K; As = N2K; aOff = aTile * 256;
        Bb = data + b * 3 * N8K; Bs = N8K; bOff = chunk * N2K;
    } else if (role == 2) {        // p1: A=data seg(b,p), B=recp seg(b,p)
        int p = r >> 3; int aTile = r & 7;
        Ab = data + b * 3 * N8K; As = N8K; aOff = p * N2K + aTile * 256;
        Bb = recp + b * 3 * N8K; Bs = N8K; bOff = p * N2K;
    } else {                       // p2: A=recp seg(b,p), B=data seg(b,p)
        int p = r >> 3; int aTile = r & 7;
        Ab = recp + b * 3 * N8K; As = N8K; aOff = p * N2K + aTile * 256;
        Bb = data + b * 3 * N8K; Bs = N8K; bOff = p * N2K;
    }

    const int tid = threadIdx.x;

    // Stage 2048 B points into LDS (8 per thread, coalesced)
    for (int k = tid; k < N2K; k += THREADS) {
        int j = bOff + k;
        float x = Bb[j], y = Bb[Bs + j], z = Bb[2 * Bs + j];
        sB[k] = make_float4(-2.f * x, -2.f * y, -2.f * z,
                            x * x + y * y + z * z);
    }

    // One A point per thread
    const int i0 = aOff + tid;
    const float ax = Ab[i0], ay = Ab[As + i0], az = Ab[2 * As + i0];
    const float na = ax * ax + ay * ay + az * az;

    __syncthreads();

    // 4 interleaved min-chains over the 2048 staged B points
    float m0 = 3.4e38f, m1 = 3.4e38f, m2 = 3.4e38f, m3 = 3.4e38f;
    #pragma unroll 4
    for (int j = 0; j < N2K; j += 4) {    // wave-uniform j -> LDS broadcast
        float4 q0 = sB[j], q1 = sB[j + 1], q2 = sB[j + 2], q3 = sB[j + 3];
        m0 = fminf(m0, fmaf(ax, q0.x, fmaf(ay, q0.y, fmaf(az, q0.z, q0.w))));
        m1 = fminf(m1, fmaf(ax, q1.x, fmaf(ay, q1.y, fmaf(az, q1.z, q1.w))));
        m2 = fminf(m2, fmaf(ax, q2.x, fmaf(ay, q2.y, fmaf(az, q2.z, q2.w))));
        m3 = fminf(m3, fmaf(ax, q3.x, fmaf(ay, q3.y, fmaf(az, q3.z, q3.w))));
    }
    const float v = na + fminf(fminf(m0, m1), fminf(m2, m3));

    if (role == 1) {
        // per-A chunk min -> ws; combined in finalize
        ws[chunk * D2MINS + b * N2K + aOff + tid] = v;
    } else {
        float s = v;
        #pragma unroll
        for (int o = 32; o > 0; o >>= 1) s += __shfl_down(s, o, 64);
        const int lane = tid & 63, wid = tid >> 6;
        if (lane == 0) sred[wid] = s;
        __syncthreads();
        if (tid == 0)
            ws[PARTIALS_OFF + bid] = (sred[0] + sred[1]) + (sred[2] + sred[3]);
    }
}

__global__ __launch_bounds__(1024) void finalize_kernel(
    const float* __restrict__ ws, float* __restrict__ out)
{
    __shared__ float sred[16];
    const int tid = threadIdx.x;
    const float* mins = ws;
    const float* partials = ws + PARTIALS_OFF;

    float s = 0.f;
    // d2: min over 4 chunks, mean over 16384
    for (int k = tid; k < D2MINS; k += 1024) {
        float v = fminf(fminf(mins[k], mins[D2MINS + k]),
                        fminf(mins[2 * D2MINS + k], mins[3 * D2MINS + k]));
        s += v * (1.f / 16384.f);
    }
    // d1 partials (mean over 8*8192)
    if (tid < 256) s += partials[tid] * (1.f / 65536.f);
    // p1,p2 partials (mean over 8*2048 per part)
    if (tid < 512) s += partials[512 + tid] * (1.f / 16384.f);

    #pragma unroll
    for (int o = 32; o > 0; o >>= 1) s += __shfl_down(s, o, 64);
    const int lane = tid & 63, wid = tid >> 6;
    if (lane == 0) sred[wid] = s;
    __syncthreads();
    if (tid == 0) {
        float tot = 0.f;
        #pragma unroll
        for (int i = 0; i < 16; ++i) tot += sred[i];
        out[0] = tot * 0.2f;   // /5
    }
}

extern "C" void kernel_launch(void* const* d_in, const int* in_sizes, int n_in,
                              void* d_out, int out_size, void* d_ws, size_t ws_size,
                              hipStream_t stream) {
    const float* data = (const float*)d_in[0];
    const float* rec  = (const float*)d_in[1];
    const float* recp = (const float*)d_in[2];
    float* out = (float*)d_out;
    float* ws  = (float*)d_ws;

    chamfer_kernel<<<NBLK, THREADS, 0, stream>>>(data, rec, recp, ws);
    finalize_kernel<<<1, 1024, 0, stream>>>(ws, out);
}

// Round 3
// 58.482 us; speedup vs baseline: 2.8353x; 1.2869x over previous
//
#include <hip/hip_runtime.h>

// Chamfer loss: global (data vs rec) + per-part (data seg vs recp seg).
// 512 uniform blocks x 256 threads; block = 512 A-points (2/thread) x
// 2048 B-points staged in LDS as float4(-2bx,-2by,-2bz,||b||^2).
// Pair cost = 3 fma + 1 min; 2 A/thread -> 8 VALU ops per LDS float4 read,
// 8 independent min-chains/thread to hide fma latency.
// d2 (rec vs data, B=8192) is split into 4 B-chunks; per-A chunk mins go
// to ws and are min-combined in finalize (fixed order, deterministic).

#define N2K 2048
#define N8K 8192
#define THREADS 256
#define NBLK 512           // 128 per role: [0,128)=d1 [128,256)=d2 [256,384)=p1 [384,512)=p2
#define D2MINS 16384       // 8 batches * 2048 rec points
#define PARTIALS_OFF 65536 // 4 chunks * 16384 floats of d2 mins first

__global__ __launch_bounds__(THREADS) void chamfer_kernel(
    const float* __restrict__ data,
    const float* __restrict__ rec,
    const float* __restrict__ recp,
    float* __restrict__ ws)
{
    __shared__ float4 sB[N2K];
    __shared__ float sred[4];

    const int bid = blockIdx.x;
    const int role = bid >> 7;     // 0=d1 1=d2 2=p1 3=p2
    const int t = bid & 127;
    const int b = t >> 4;          // batch
    const int r = t & 15;

    const float* Ab; int As; int aOff;
    const float* Bb; int Bs; int bOff;
    int chunk = 0, aTile = 0;

    if (role == 0) {               // d1: A=data[b] (16 tiles of 512), B=rec[b]
        Ab = data + b * 3 * N8K; As = N8K; aOff = r * 512;
        Bb = rec  + b * 3 * N2K; Bs = N2K; bOff = 0;
    } else if (role == 1) {        // d2: A=rec[b] (4 tiles), B=data[b] chunk (4)
        chunk = r >> 2; aTile = r & 3;
        Ab = rec  + b * 3 * N2K; As = N2K; aOff = aTile * 512;
        Bb = data + b * 3 * N8K; Bs = N8K; bOff = chunk * N2K;
    } else if (role == 2) {        // p1: A=data seg(b,p), B=recp seg(b,p)
        int p = r >> 2; aTile = r & 3;
        Ab = data + b * 3 * N8K; As = N8K; aOff = p * N2K + aTile * 512;
        Bb = recp + b * 3 * N8K; Bs = N8K; bOff = p * N2K;
    } else {                       // p2: A=recp seg(b,p), B=data seg(b,p)
        int p = r >> 2; aTile = r & 3;
        Ab = recp + b * 3 * N8K; As = N8K; aOff = p * N2K + aTile * 512;
        Bb = data + b * 3 * N8K; Bs = N8K; bOff = p * N2K;
    }

    const int tid = threadIdx.x;

    // Stage 2048 B points into LDS (8 per thread, coalesced)
    for (int k = tid; k < N2K; k += THREADS) {
        int j = bOff + k;
        float x = Bb[j], y = Bb[Bs + j], z = Bb[2 * Bs + j];
        sB[k] = make_float4(-2.f * x, -2.f * y, -2.f * z,
                            x * x + y * y + z * z);
    }

    // Two A points per thread (coalesced: tid, tid+256)
    const int i0 = aOff + tid;
    const int i1 = aOff + THREADS + tid;
    const float a0x = Ab[i0], a0y = Ab[As + i0], a0z = Ab[2 * As + i0];
    const float a1x = Ab[i1], a1y = Ab[As + i1], a1z = Ab[2 * As + i1];
    const float na0 = a0x * a0x + a0y * a0y + a0z * a0z;
    const float na1 = a1x * a1x + a1y * a1y + a1z * a1z;

    __syncthreads();

    // 8 interleaved min-chains (2 A x 4 B in flight)
    float p00 = 3.4e38f, p01 = 3.4e38f, p02 = 3.4e38f, p03 = 3.4e38f;
    float p10 = 3.4e38f, p11 = 3.4e38f, p12 = 3.4e38f, p13 = 3.4e38f;
    #pragma unroll 2
    for (int j = 0; j < N2K; j += 4) {    // wave-uniform j -> LDS broadcast
        float4 q0 = sB[j], q1 = sB[j + 1], q2 = sB[j + 2], q3 = sB[j + 3];
        p00 = fminf(p00, fmaf(a0x, q0.x, fmaf(a0y, q0.y, fmaf(a0z, q0.z, q0.w))));
        p01 = fminf(p01, fmaf(a0x, q1.x, fmaf(a0y, q1.y, fmaf(a0z, q1.z, q1.w))));
        p02 = fminf(p02, fmaf(a0x, q2.x, fmaf(a0y, q2.y, fmaf(a0z, q2.z, q2.w))));
        p03 = fminf(p03, fmaf(a0x, q3.x, fmaf(a0y, q3.y, fmaf(a0z, q3.z, q3.w))));
        p10 = fminf(p10, fmaf(a1x, q0.x, fmaf(a1y, q0.y, fmaf(a1z, q0.z, q0.w))));
        p11 = fminf(p11, fmaf(a1x, q1.x, fmaf(a1y, q1.y, fmaf(a1z, q1.z, q1.w))));
        p12 = fminf(p12, fmaf(a1x, q2.x, fmaf(a1y, q2.y, fmaf(a1z, q2.z, q2.w))));
        p13 = fminf(p13, fmaf(a1x, q3.x, fmaf(a1y, q3.y, fmaf(a1z, q3.z, q3.w))));
    }
    const float v0 = na0 + fminf(fminf(p00, p01), fminf(p02, p03));
    const float v1 = na1 + fminf(fminf(p10, p11), fminf(p12, p13));

    if (role == 1) {
        // per-A chunk min -> ws; combined in finalize
        int base = chunk * D2MINS + b * N2K + aTile * 512 + tid;
        ws[base] = v0;
        ws[base + THREADS] = v1;
    } else {
        float s = v0 + v1;
        #pragma unroll
        for (int o = 32; o > 0; o >>= 1) s += __shfl_down(s, o, 64);
        const int lane = tid & 63, wid = tid >> 6;
        if (lane == 0) sred[wid] = s;
        __syncthreads();
        if (tid == 0)
            ws[PARTIALS_OFF + bid] = (sred[0] + sred[1]) + (sred[2] + sred[3]);
    }
}

__global__ __launch_bounds__(1024) void finalize_kernel(
    const float* __restrict__ ws, float* __restrict__ out)
{
    __shared__ float sred[16];
    const int tid = threadIdx.x;
    const float* mins = ws;
    const float* partials = ws + PARTIALS_OFF;

    float s = 0.f;
    // d2: min over 4 chunks, mean over 16384
    for (int k = tid; k < D2MINS; k += 1024) {
        float v = fminf(fminf(mins[k], mins[D2MINS + k]),
                        fminf(mins[2 * D2MINS + k], mins[3 * D2MINS + k]));
        s += v * (1.f / 16384.f);
    }
    // d1 partials (mean over 8*8192)
    if (tid < 128) s += partials[tid] * (1.f / 65536.f);
    // p1,p2 partials (mean over 8*2048 per part)
    if (tid >= 256 && tid < 512) s += partials[tid] * (1.f / 16384.f);

    #pragma unroll
    for (int o = 32; o > 0; o >>= 1) s += __shfl_down(s, o, 64);
    const int lane = tid & 63, wid = tid >> 6;
    if (lane == 0) sred[wid] = s;
    __syncthreads();
    if (tid == 0) {
        float tot = 0.f;
        #pragma unroll
        for (int i = 0; i < 16; ++i) tot += sred[i];
        out[0] = tot * 0.2f;   // /5
    }
}

extern "C" void kernel_launch(void* const* d_in, const int* in_sizes, int n_in,
                              void* d_out, int out_size, void* d_ws, size_t ws_size,
                              hipStream_t stream) {
    const float* data = (const float*)d_in[0];
    const float* rec  = (const float*)d_in[1];
    const float* recp = (const float*)d_in[2];
    float* out = (float*)d_out;
    float* ws  = (float*)d_ws;

    chamfer_kernel<<<NBLK, THREADS, 0, stream>>>(data, rec, recp, ws);
    finalize_kernel<<<1, 1024, 0, stream>>>(ws, out);
}

// Round 4
// 49.482 us; speedup vs baseline: 3.3510x; 1.1819x over previous
//
#include <hip/hip_runtime.h>

// Chamfer loss: global (data vs rec) + per-part (data seg vs recp seg).
// 1024 uniform blocks x 256 threads; block = 1024 A-points (4/thread) x
// 512 B-points staged in LDS as float4(-2bx,-2by,-2bz,||b||^2).
// Pair cost = 3 fma + 1 min; 4 A/thread -> 16 VALU ops per ds_read_b128.
// Every role is B-chunked: blocks write per-A chunk-mins to ws
// (chunk-major, coalesced); finalize1 does min-over-chunks + weighted
// block sums; finalize2 folds 256 partials. Fixed order -> deterministic.

#define N2K 2048
#define N8K 8192
#define THREADS 256
#define ABLK 1024
#define BBLK 512
// ws float layout:
//   [0,       262144) d1 mins: c*65536 + b*8192 + a   (C=4)
//   [262144,  524288) d2 mins: c*16384 + b*2048 + a   (C=16)
//   [524288,  786432) p1 mins: c*65536 + b*8192 + a   (C=4)
//   [786432, 1048576) p2 mins: c*65536 + b*8192 + a   (C=4)
//   [1048576, 1048832) 256 finalize1 partials
#define D1_BASE 0
#define D2_BASE 262144
#define P1_BASE 524288
#define P2_BASE 786432
#define PART_BASE 1048576

__global__ __launch_bounds__(THREADS) void chamfer_kernel(
    const float* __restrict__ data,
    const float* __restrict__ rec,
    const float* __restrict__ recp,
    float* __restrict__ ws)
{
    __shared__ float4 sB[BBLK];

    const int bid = blockIdx.x;
    const int role = bid >> 8;     // 0=d1 1=d2 2=p1 3=p2 (256 blocks each)
    const int t = bid & 255;
    const int b = t >> 5;          // batch
    const int r = t & 31;

    const float* Ab; int As; int aOff;
    const float* Bb; int Bs; int bOff;
    int wbase;

    if (role == 0) {               // d1: A=data[b], B=rec[b]
        int At = r >> 2, Bc = r & 3;          // 8 A-tiles x 4 B-chunks
        Ab = data + b * 3 * N8K; As = N8K; aOff = At * ABLK;
        Bb = rec  + b * 3 * N2K; Bs = N2K; bOff = Bc * BBLK;
        wbase = D1_BASE + Bc * 65536 + b * N8K + aOff;
    } else if (role == 1) {        // d2: A=rec[b], B=data[b]
        int At = r >> 4, Bc = r & 15;         // 2 A-tiles x 16 B-chunks
        Ab = rec  + b * 3 * N2K; As = N2K; aOff = At * ABLK;
        Bb = data + b * 3 * N8K; Bs = N8K; bOff = Bc * BBLK;
        wbase = D2_BASE + Bc * 16384 + b * N2K + aOff;
    } else if (role == 2) {        // p1: A=data seg(b,p), B=recp seg(b,p)
        int p = r >> 3, r2 = r & 7;
        int At = r2 >> 2, Bc = r2 & 3;        // 2 A-tiles x 4 B-chunks
        Ab = data + b * 3 * N8K; As = N8K; aOff = p * N2K + At * ABLK;
        Bb = recp + b * 3 * N8K; Bs = N8K; bOff = p * N2K + Bc * BBLK;
        wbase = P1_BASE + Bc * 65536 + b * N8K + aOff;
    } else {                       // p2: A=recp seg(b,p), B=data seg(b,p)
        int p = r >> 3, r2 = r & 7;
        int At = r2 >> 2, Bc = r2 & 3;
        Ab = recp + b * 3 * N8K; As = N8K; aOff = p * N2K + At * ABLK;
        Bb = data + b * 3 * N8K; Bs = N8K; bOff = p * N2K + Bc * BBLK;
        wbase = P2_BASE + Bc * 65536 + b * N8K + aOff;
    }

    const int tid = threadIdx.x;

    // Stage 512 B points into LDS (2 per thread, coalesced)
    for (int k = tid; k < BBLK; k += THREADS) {
        int j = bOff + k;
        float x = Bb[j], y = Bb[Bs + j], z = Bb[2 * Bs + j];
        sB[k] = make_float4(-2.f * x, -2.f * y, -2.f * z,
                            x * x + y * y + z * z);
    }

    // Four A points per thread (coalesced: tid + i*256)
    float ax[4], ay[4], az[4], na[4];
    #pragma unroll
    for (int i = 0; i < 4; ++i) {
        int idx = aOff + i * THREADS + tid;
        ax[i] = Ab[idx]; ay[i] = Ab[As + idx]; az[i] = Ab[2 * As + idx];
        na[i] = ax[i] * ax[i] + ay[i] * ay[i] + az[i] * az[i];
    }

    __syncthreads();

    // 16 interleaved min-chains (4 A x 4 B in flight)
    float m[4][4];
    #pragma unroll
    for (int i = 0; i < 4; ++i)
        #pragma unroll
        for (int j = 0; j < 4; ++j) m[i][j] = 3.4e38f;

    #pragma unroll 2
    for (int j = 0; j < BBLK; j += 4) {   // wave-uniform j -> LDS broadcast
        float4 q[4];
        #pragma unroll
        for (int bi = 0; bi < 4; ++bi) q[bi] = sB[j + bi];
        #pragma unroll
        for (int ai = 0; ai < 4; ++ai)
            #pragma unroll
            for (int bi = 0; bi < 4; ++bi)
                m[ai][bi] = fminf(m[ai][bi],
                    fmaf(ax[ai], q[bi].x,
                    fmaf(ay[ai], q[bi].y,
                    fmaf(az[ai], q[bi].z, q[bi].w))));
    }

    #pragma unroll
    for (int ai = 0; ai < 4; ++ai) {
        float v = na[ai] + fminf(fminf(m[ai][0], m[ai][1]),
                                 fminf(m[ai][2], m[ai][3]));
        ws[wbase + ai * THREADS + tid] = v;   // coalesced
    }
}

__global__ __launch_bounds__(THREADS) void finalize1_kernel(
    const float* __restrict__ ws, float* __restrict__ part)
{
    __shared__ float sred[4];
    const int blk = blockIdx.x;        // 256 blocks: 64 per role
    const int role = blk >> 6;
    const int k = blk & 63;
    const int tid = threadIdx.x;

    float s = 0.f;
    float w;
    if (role == 1) {                   // d2: 256 A per block, C=16
        int a = k * 256 + tid;
        float v = 3.4e38f;
        #pragma unroll
        for (int c = 0; c < 16; ++c)
            v = fminf(v, ws[D2_BASE + c * 16384 + a]);
        s = v; w = 1.f / 16384.f;
    } else {                           // d1/p1/p2: 1024 A per block, C=4
        int base = (role == 0) ? D1_BASE : (role == 2) ? P1_BASE : P2_BASE;
        w = (role == 0) ? (1.f / 65536.f) : (1.f / 16384.f);
        #pragma unroll
        for (int i = 0; i < 4; ++i) {
            int a = k * 1024 + i * 256 + tid;
            float v = fminf(fminf(ws[base + a],          ws[base + 65536 + a]),
                            fminf(ws[base + 131072 + a], ws[base + 196608 + a]));
            s += v;
        }
    }
    s *= w;

    #pragma unroll
    for (int o = 32; o > 0; o >>= 1) s += __shfl_down(s, o, 64);
    const int lane = tid & 63, wid = tid >> 6;
    if (lane == 0) sred[wid] = s;
    __syncthreads();
    if (tid == 0)
        part[blk] = (sred[0] + sred[1]) + (sred[2] + sred[3]);
}

__global__ __launch_bounds__(THREADS) void finalize2_kernel(
    const float* __restrict__ part, float* __restrict__ out)
{
    __shared__ float sred[4];
    const int tid = threadIdx.x;
    float s = part[tid];
    #pragma unroll
    for (int o = 32; o > 0; o >>= 1) s += __shfl_down(s, o, 64);
    const int lane = tid & 63, wid = tid >> 6;
    if (lane == 0) sred[wid] = s;
    __syncthreads();
    if (tid == 0)
        out[0] = ((sred[0] + sred[1]) + (sred[2] + sred[3])) * 0.2f;  // /5
}

extern "C" void kernel_launch(void* const* d_in, const int* in_sizes, int n_in,
                              void* d_out, int out_size, void* d_ws, size_t ws_size,
                              hipStream_t stream) {
    const float* data = (const float*)d_in[0];
    const float* rec  = (const float*)d_in[1];
    const float* recp = (const float*)d_in[2];
    float* out = (float*)d_out;
    float* ws  = (float*)d_ws;

    chamfer_kernel<<<1024, THREADS, 0, stream>>>(data, rec, recp, ws);
    finalize1_kernel<<<256, THREADS, 0, stream>>>(ws, ws + PART_BASE);
    finalize2_kernel<<<1, THREADS, 0, stream>>>(ws + PART_BASE, out);
}

// Round 5
// 48.344 us; speedup vs baseline: 3.4299x; 1.0236x over previous
//
#include <hip/hip_runtime.h>

// Chamfer loss: global (data vs rec) + per-part (data seg vs recp seg).
// 512 uniform blocks x 256 threads; block = 2048 A-points (8/thread) x
// 512 B-points. B staged in LDS as PAIRS:
//   sP[jp] = {-2x0, -2x1, -2y0, -2y1}   sQ[jp] = {-2z0, -2z1, nb0, nb1}
// Inner math on float2 via __builtin_elementwise_fma -> v_pk_fma_f32,
// min via fminf(fminf(d.x,d.y),m) -> v_min3_f32:
//   per (8A x 2B): 2 ds_read_b128 + 24 pk_fma + 8 min3 = 2 VALU/pair.
// All roles B-chunked; per-A chunk-mins to ws (chunk-major, coalesced);
// finalize1 min-over-chunks + weighted sums; finalize2 folds partials.
// Fixed reduction order -> deterministic.

#define N2K 2048
#define N8K 8192
#define THREADS 256
#define ABLK 2048          // A points per block (8 per thread)
#define BBLK 512           // B points per block (256 pairs)
// ws float layout (same as previous round):
//   [0,       262144) d1 mins: c*65536 + b*8192 + a   (C=4)
//   [262144,  524288) d2 mins: c*16384 + b*2048 + a   (C=16)
//   [524288,  786432) p1 mins: c*65536 + b*8192 + a   (C=4)
//   [786432, 1048576) p2 mins: c*65536 + b*8192 + a   (C=4)
//   [1048576, 1048832) 256 finalize1 partials
#define D1_BASE 0
#define D2_BASE 262144
#define P1_BASE 524288
#define P2_BASE 786432
#define PART_BASE 1048576

typedef float f2 __attribute__((ext_vector_type(2)));

__global__ __launch_bounds__(THREADS) void chamfer_kernel(
    const float* __restrict__ data,
    const float* __restrict__ rec,
    const float* __restrict__ recp,
    float* __restrict__ ws)
{
    __shared__ float4 sP[BBLK / 2];   // {-2x0,-2x1,-2y0,-2y1} per pair
    __shared__ float4 sQ[BBLK / 2];   // {-2z0,-2z1, nb0, nb1} per pair

    const int bid = blockIdx.x;       // 512 blocks, 128 per role
    const int role = bid >> 7;        // 0=d1 1=d2 2=p1 3=p2
    const int r = bid & 127;
    const int b = r >> 4;             // batch
    const int rr = r & 15;

    const float* Ab; int As; int aOff;
    const float* Bb; int Bs; int bOff;
    int wbase;

    if (role == 0) {                  // d1: A=data[b], B=rec[b]
        int At = rr >> 2, Bc = rr & 3;           // 4 A-tiles x 4 B-chunks
        Ab = data + b * 3 * N8K; As = N8K; aOff = At * ABLK;
        Bb = rec  + b * 3 * N2K; Bs = N2K; bOff = Bc * BBLK;
        wbase = D1_BASE + Bc * 65536 + b * N8K + aOff;
    } else if (role == 1) {           // d2: A=rec[b], B=data[b]
        int Bc = rr;                             // 1 A-tile x 16 B-chunks
        Ab = rec  + b * 3 * N2K; As = N2K; aOff = 0;
        Bb = data + b * 3 * N8K; Bs = N8K; bOff = Bc * BBLK;
        wbase = D2_BASE + Bc * 16384 + b * N2K;
    } else if (role == 2) {           // p1: A=data seg(b,p), B=recp seg(b,p)
        int p = rr >> 2, Bc = rr & 3;            // 4 parts x 4 B-chunks
        Ab = data + b * 3 * N8K; As = N8K; aOff = p * N2K;
        Bb = recp + b * 3 * N8K; Bs = N8K; bOff = p * N2K + Bc * BBLK;
        wbase = P1_BASE + Bc * 65536 + b * N8K + p * N2K;
    } else {                          // p2: A=recp seg(b,p), B=data seg(b,p)
        int p = rr >> 2, Bc = rr & 3;
        Ab = recp + b * 3 * N8K; As = N8K; aOff = p * N2K;
        Bb = data + b * 3 * N8K; Bs = N8K; bOff = p * N2K + Bc * BBLK;
        wbase = P2_BASE + Bc * 65536 + b * N8K + p * N2K;
    }

    const int tid = threadIdx.x;

    // Stage 512 B points as 256 pairs (1 pair per thread)
    {
        int j0 = bOff + 2 * tid, j1 = j0 + 1;
        float x0 = Bb[j0], y0 = Bb[Bs + j0], z0 = Bb[2 * Bs + j0];
        float x1 = Bb[j1], y1 = Bb[Bs + j1], z1 = Bb[2 * Bs + j1];
        sP[tid] = make_float4(-2.f * x0, -2.f * x1, -2.f * y0, -2.f * y1);
        sQ[tid] = make_float4(-2.f * z0, -2.f * z1,
                              x0 * x0 + y0 * y0 + z0 * z0,
                              x1 * x1 + y1 * y1 + z1 * z1);
    }

    // Eight A points per thread (coalesced: tid + i*256), pre-packed {a,a}
    f2 ax2[8], ay2[8], az2[8];
    float na[8], m[8];
    #pragma unroll
    for (int i = 0; i < 8; ++i) {
        int idx = aOff + i * THREADS + tid;
        float x = Ab[idx], y = Ab[As + idx], z = Ab[2 * As + idx];
        ax2[i] = (f2){x, x}; ay2[i] = (f2){y, y}; az2[i] = (f2){z, z};
        na[i] = x * x + y * y + z * z;
        m[i] = 3.4e38f;
    }

    __syncthreads();

    // 256 pair-groups; per group: 2 ds_read_b128 + 8 x (3 pk_fma + 1 min3)
    #pragma unroll 2
    for (int jp = 0; jp < BBLK / 2; ++jp) {   // wave-uniform -> LDS broadcast
        float4 P = sP[jp], Q = sQ[jp];
        f2 px = (f2){P.x, P.y}, py = (f2){P.z, P.w};
        f2 pz = (f2){Q.x, Q.y}, pw = (f2){Q.z, Q.w};
        #pragma unroll
        for (int i = 0; i < 8; ++i) {
            f2 d = __builtin_elementwise_fma(az2[i], pz, pw);
            d = __builtin_elementwise_fma(ay2[i], py, d);
            d = __builtin_elementwise_fma(ax2[i], px, d);
            m[i] = fminf(fminf(d.x, d.y), m[i]);   // -> v_min3_f32
        }
    }

    #pragma unroll
    for (int i = 0; i < 8; ++i)
        ws[wbase + i * THREADS + tid] = na[i] + m[i];   // coalesced
}

__global__ __launch_bounds__(THREADS) void finalize1_kernel(
    const float* __restrict__ ws, float* __restrict__ part)
{
    __shared__ float sred[4];
    const int blk = blockIdx.x;        // 256 blocks: 64 per role
    const int role = blk >> 6;
    const int k = blk & 63;
    const int tid = threadIdx.x;

    float s = 0.f;
    float w;
    if (role == 1) {                   // d2: 256 A per block, C=16
        int a = k * 256 + tid;
        float v = 3.4e38f;
        #pragma unroll
        for (int c = 0; c < 16; ++c)
            v = fminf(v, ws[D2_BASE + c * 16384 + a]);
        s = v; w = 1.f / 16384.f;
    } else {                           // d1/p1/p2: 1024 A per block, C=4
        int base = (role == 0) ? D1_BASE : (role == 2) ? P1_BASE : P2_BASE;
        w = (role == 0) ? (1.f / 65536.f) : (1.f / 16384.f);
        #pragma unroll
        for (int i = 0; i < 4; ++i) {
            int a = k * 1024 + i * 256 + tid;
            float v = fminf(fminf(ws[base + a],          ws[base + 65536 + a]),
                            fminf(ws[base + 131072 + a], ws[base + 196608 + a]));
            s += v;
        }
    }
    s *= w;

    #pragma unroll
    for (int o = 32; o > 0; o >>= 1) s += __shfl_down(s, o, 64);
    const int lane = tid & 63, wid = tid >> 6;
    if (lane == 0) sred[wid] = s;
    __syncthreads();
    if (tid == 0)
        part[blk] = (sred[0] + sred[1]) + (sred[2] + sred[3]);
}

__global__ __launch_bounds__(THREADS) void finalize2_kernel(
    const float* __restrict__ part, float* __restrict__ out)
{
    __shared__ float sred[4];
    const int tid = threadIdx.x;
    float s = part[tid];
    #pragma unroll
    for (int o = 32; o > 0; o >>= 1) s += __shfl_down(s, o, 64);
    const int lane = tid & 63, wid = tid >> 6;
    if (lane == 0) sred[wid] = s;
    __syncthreads();
    if (tid == 0)
        out[0] = ((sred[0] + sred[1]) + (sred[2] + sred[3])) * 0.2f;  // /5
}

extern "C" void kernel_launch(void* const* d_in, const int* in_sizes, int n_in,
                              void* d_out, int out_size, void* d_ws, size_t ws_size,
                              hipStream_t stream) {
    const float* data = (const float*)d_in[0];
    const float* rec  = (const float*)d_in[1];
    const float* recp = (const float*)d_in[2];
    float* out = (float*)d_out;
    float* ws  = (float*)d_ws;

    chamfer_kernel<<<512, THREADS, 0, stream>>>(data, rec, recp, ws);
    finalize1_kernel<<<256, THREADS, 0, stream>>>(ws, ws + PART_BASE);
    finalize2_kernel<<<1, THREADS, 0, stream>>>(ws + PART_BASE, out);
}